// Round 12
// baseline (168.799 us; speedup 1.0000x reference)
//
#include <hip/hip_runtime.h>
#include <hip/hip_bf16.h>
#include <stdint.h>

#define M_TOT 16384
#define N_TOT 3072
#define K_TOT 768

#define BM 256
#define BN 256
#define BK 32
#define NT (K_TOT / BK)   // 24 K-tiles

typedef __attribute__((ext_vector_type(8))) short short8;
typedef __attribute__((ext_vector_type(4))) float f32x4;

__device__ __forceinline__ unsigned short f2bf(float f) {
    union { float f; unsigned u; } v;
    v.f = f;
    unsigned r = v.u + 0x7FFFu + ((v.u >> 16) & 1u);  // round-to-nearest-even
    return (unsigned short)(r >> 16);
}

// ---------------- kernel 1: x fp32 -> bf16 (vectorized) ----------------------
__global__ __launch_bounds__(256) void cvt_x_kernel(const float* __restrict__ x,
                                                    unsigned short* __restrict__ xb,
                                                    int n8) {
    int i = blockIdx.x * blockDim.x + threadIdx.x;
    int stride = gridDim.x * blockDim.x;
    const float4* xv = reinterpret_cast<const float4*>(x);
    uint4* ov = reinterpret_cast<uint4*>(xb);
    for (; i < n8; i += stride) {
        float4 a = xv[2 * i], b = xv[2 * i + 1];
        uint4 o;
        o.x = (unsigned)f2bf(a.x) | ((unsigned)f2bf(a.y) << 16);
        o.y = (unsigned)f2bf(a.z) | ((unsigned)f2bf(a.w) << 16);
        o.z = (unsigned)f2bf(b.x) | ((unsigned)f2bf(b.y) << 16);
        o.w = (unsigned)f2bf(b.z) | ((unsigned)f2bf(b.w) << 16);
        ov[i] = o;
    }
}

// ---------------- kernel 2a: W_tilde = A @ B (2048x1152x64, fp32) ------------
__global__ __launch_bounds__(256) void wtilde_gemm_kernel(const float* __restrict__ Af,
                                                          const float* __restrict__ Bf,
                                                          float* __restrict__ Wtmp) {
    __shared__ float As[64][68];
    __shared__ float Bs[64][68];
    const int tid = threadIdx.x;
    const int bp = blockIdx.x / 18, bq = blockIdx.x % 18;
    const int p0 = bp * 64, q0 = bq * 64;
    {
        #pragma unroll
        for (int i = 0; i < 4; ++i) {
            int idx = i * 256 + tid;
            int row = idx >> 4, c4 = (idx & 15) * 4;
            f32x4 v = *reinterpret_cast<const f32x4*>(&Af[(size_t)(p0 + row) * 64 + c4]);
            As[c4 + 0][row] = v[0]; As[c4 + 1][row] = v[1];
            As[c4 + 2][row] = v[2]; As[c4 + 3][row] = v[3];
        }
    }
    {
        #pragma unroll
        for (int l = 0; l < 4; ++l) {
            int idx = l * 256 + tid;
            int k = idx >> 4, c4 = (idx & 15) * 4;
            *reinterpret_cast<f32x4*>(&Bs[k][c4]) =
                *reinterpret_cast<const f32x4*>(&Bf[(size_t)k * 1152 + q0 + c4]);
        }
    }
    __syncthreads();
    float acc[4][4] = {};
    const int rb = (tid >> 4) * 4;
    const int cb = (tid & 15) * 4;
    #pragma unroll
    for (int k = 0; k < 64; ++k) {
        f32x4 a = *reinterpret_cast<const f32x4*>(&As[k][rb]);
        f32x4 b = *reinterpret_cast<const f32x4*>(&Bs[k][cb]);
        #pragma unroll
        for (int i = 0; i < 4; ++i)
            #pragma unroll
            for (int j = 0; j < 4; ++j)
                acc[i][j] = fmaf(a[i], b[j], acc[i][j]);
    }
    #pragma unroll
    for (int i = 0; i < 4; ++i) {
        f32x4 o = {acc[i][0], acc[i][1], acc[i][2], acc[i][3]};
        *reinterpret_cast<f32x4*>(&Wtmp[(size_t)(p0 + rb + i) * 1152 + q0 + cb]) = o;
    }
}

// ---------------- kernel 2b: Kronecker permute + Sparse + bf16 + transpose ---
__global__ __launch_bounds__(256) void permute_w_kernel(const float* __restrict__ Wtmp,
                                                        const float* __restrict__ Sp,
                                                        unsigned short* __restrict__ Wt) {
    __shared__ float T[64][65];
    const int tid = threadIdx.x;
    const int r0 = (blockIdx.x % 12) * 64;
    const int c0 = (blockIdx.x / 12) * 64;
    #pragma unroll
    for (int l = 0; l < 16; ++l) {
        int i = l * 4 + (tid >> 6);
        int j = tid & 63;
        int r = r0 + i, c = c0 + j;
        int m1 = r / 24, m2 = r - m1 * 24;
        int n1 = c / 48, n2 = c - n1 * 48;
        T[i][j] = Wtmp[(size_t)(m1 * 64 + n1) * 1152 + m2 * 48 + n2]
                + Sp[(size_t)r * 3072 + c];
    }
    __syncthreads();
    #pragma unroll
    for (int u0 = 0; u0 < 2; ++u0) {
        int u = u0 * 256 + tid;
        int jj = u >> 3;
        int ii = u & 7;
        unsigned w[4];
        #pragma unroll
        for (int t = 0; t < 4; ++t) {
            unsigned lo = f2bf(T[ii * 8 + 2 * t][jj]);
            unsigned hi = f2bf(T[ii * 8 + 2 * t + 1][jj]);
            w[t] = lo | (hi << 16);
        }
        uint4 o = {w[0], w[1], w[2], w[3]};
        *reinterpret_cast<uint4*>(&Wt[(size_t)(c0 + jj) * 768 + r0 + ii * 8]) = o;
    }
}

// ---------------- kernel 3: PERSISTENT 256-block GEMM, 3 bn-tiles/block ------
// A  : [16384][768] bf16; Bt : [3072][768] bf16; C = A@Bt^T + bias.
// R11 analysis: with 1 block/CU, each block-generation's epilogue (~12us)
// serializes before the next generation's loop -> 3x(25+12) = 112us.  Fix:
// grid = 256 (one generation).  Each block keeps its bm (A-panel L2 reuse)
// and sweeps 3 bn tiles; tile i's C-stores stay OUTSTANDING while tile i+1
// stages and computes -- the vmcnt FIFO means the prologue's vmcnt(8) already
// guarantees "all stores + tile-0 loads done" (stores are oldest in queue).
// Epilogue is paid serially only once, at kernel end.
__device__ __forceinline__ void gld16(const void* g, void* l) {
    __builtin_amdgcn_global_load_lds(
        (const __attribute__((address_space(1))) void*)g,
        (__attribute__((address_space(3))) void*)l, 16, 0, 0);
}

__global__ __launch_bounds__(512, 2) void gemm_bt_kernel(
    const unsigned short* __restrict__ A, const unsigned short* __restrict__ Bt,
    const float* __restrict__ bias, float* __restrict__ C) {
    // 4 buffers x (A 16KB + B 16KB) = 128 KB
    __shared__ unsigned short As[4][BM * BK];
    __shared__ unsigned short Bs[4][BN * BK];

    const int tid = threadIdx.x;
    const int lane = tid & 63;
    const int wid = tid >> 6;      // 0..7
    const int wr = wid >> 2;       // 0..1  (M half)
    const int wc = wid & 3;        // 0..3  (N quarter)

    // persistent mapping: q = bn-quad (XCD x hosts only q = x&3 -> one shared
    // 384KB B-panel per step, L2-resident); bm = b>>2 (A-panel reused x3)
    const int b = blockIdx.x;
    const int q = b & 3;
    const int bm = b >> 2;         // 0..63
    const int brow = bm * BM;

    // ---- staging geometry (linear LDS dest, pre-swizzled global source) ----
    const int srow = tid >> 2;                                   // 0..127
    const int soff = (((tid & 3) ^ ((tid >> 3) & 3)) << 4);      // bytes
    const char* pA = (const char*)A + ((size_t)(brow + srow) * K_TOT) * 2 + soff;
    const size_t row128 = (size_t)128 * K_TOT * 2;
    const int tid16 = tid * 16;
    const char* pB;   // set per tile

#define STAGE_AH(u) do { const char* s_ = pA + (size_t)(u) * (BK * 2);           \
        gld16(s_,          (char*)&As[(u) & 3][0] + tid16);                      \
        gld16(s_ + row128, (char*)&As[(u) & 3][0] + tid16 + 8192); } while (0)
#define STAGE_BH(u) do { const char* s_ = pB + (size_t)(u) * (BK * 2);           \
        gld16(s_,          (char*)&Bs[(u) & 3][0] + tid16);                      \
        gld16(s_ + row128, (char*)&Bs[(u) & 3][0] + tid16 + 8192); } while (0)

    // ---- fragment reads: phys byte = row*64 + ((js ^ ((row>>1)&3))<<4) ------
    const int la = lane & 15;
    const int g4 = lane >> 4;
    const int swb = ((g4 ^ ((lane >> 1) & 3)) << 4);   // byte in row
#define FRAG_A(bu, r) (*(const short8*)((const char*)&As[bu][0] + (r) * 64 + swb))
#define FRAG_B(bu, r) (*(const short8*)((const char*)&Bs[bu][0] + (r) * 64 + swb))

#define LGKM0_FENCE() do {                                                       \
        asm volatile("s_waitcnt lgkmcnt(0)" ::: "memory");                       \
        __builtin_amdgcn_sched_barrier(0); } while (0)

    const int arow = wr * 128;
    const int bcolw = wc * 64;
    f32x4 acc[8][4];

    #pragma unroll 1
    for (int it = 0; it < 3; ++it) {
        const int bcol = (q * 3 + it) * BN;
        pB = (const char*)Bt + ((size_t)(bcol + srow) * K_TOT) * 2 + soff;

        #pragma unroll
        for (int m = 0; m < 8; ++m)
            #pragma unroll
            for (int n = 0; n < 4; ++n)
                acc[m][n] = (f32x4){0.f, 0.f, 0.f, 0.f};

        // prologue: stage tiles 0,1,2.  vmcnt(8): FIFO -> any outstanding
        // C-stores from the previous tile + tile-0's 4 loads are complete.
        STAGE_AH(0); STAGE_BH(0);
        STAGE_AH(1); STAGE_BH(1);
        STAGE_AH(2); STAGE_BH(2);
        asm volatile("s_waitcnt vmcnt(8)" ::: "memory");
        __builtin_amdgcn_s_barrier();

        for (int t = 0; t < NT; ++t) {
            const int bu = t & 3;
            short8 a0[4], b0[4];
            // ================= phase A: quadrant m0-3 x n0-3 =================
            #pragma unroll
            for (int n = 0; n < 4; ++n) b0[n] = FRAG_B(bu, bcolw + n * 16 + la);
            #pragma unroll
            for (int m = 0; m < 4; ++m) a0[m] = FRAG_A(bu, arow + m * 16 + la);
            if (t < NT - 3) STAGE_AH(t + 3);
            __builtin_amdgcn_s_barrier();
            LGKM0_FENCE();
            __builtin_amdgcn_s_setprio(1);
            #pragma unroll
            for (int m = 0; m < 4; ++m)
                #pragma unroll
                for (int n = 0; n < 4; ++n)
                    acc[m][n] = __builtin_amdgcn_mfma_f32_16x16x32_bf16(
                        b0[n], a0[m], acc[m][n], 0, 0, 0);   // SWAPPED operands
            __builtin_amdgcn_s_setprio(0);
            __builtin_amdgcn_s_barrier();
            // ================= phase B: quadrant m4-7 x n0-3 =================
            #pragma unroll
            for (int m = 0; m < 4; ++m) a0[m] = FRAG_A(bu, arow + 64 + m * 16 + la);
            if (t < NT - 3) STAGE_BH(t + 3);
            if (t < NT - 3)       asm volatile("s_waitcnt vmcnt(8)" ::: "memory");
            else if (t == NT - 3) asm volatile("s_waitcnt vmcnt(4)" ::: "memory");
            else if (t == NT - 2) asm volatile("s_waitcnt vmcnt(0)" ::: "memory");
            __builtin_amdgcn_s_barrier();
            LGKM0_FENCE();
            __builtin_amdgcn_s_setprio(1);
            #pragma unroll
            for (int m = 0; m < 4; ++m)
                #pragma unroll
                for (int n = 0; n < 4; ++n)
                    acc[4 + m][n] = __builtin_amdgcn_mfma_f32_16x16x32_bf16(
                        b0[n], a0[m], acc[4 + m][n], 0, 0, 0);   // SWAPPED
            __builtin_amdgcn_s_setprio(0);
            __builtin_amdgcn_s_barrier();
        }

        // ---- epilogue: lane owns M-row (la) x 4 N-cols (g4*4+j); stores are
        // left outstanding -- next tile's prologue vmcnt covers them. --------
        #pragma unroll
        for (int n = 0; n < 4; ++n) {
            const int gc = bcol + bcolw + n * 16 + g4 * 4;
            const f32x4 bv = *reinterpret_cast<const f32x4*>(&bias[gc]);
            #pragma unroll
            for (int m = 0; m < 8; ++m) {
                const int gr = brow + arow + m * 16 + la;
                f32x4 o = {acc[m][n][0] + bv[0], acc[m][n][1] + bv[1],
                           acc[m][n][2] + bv[2], acc[m][n][3] + bv[3]};
                *reinterpret_cast<f32x4*>(&C[(size_t)gr * N_TOT + gc]) = o;
            }
        }
    }
#undef STAGE_AH
#undef STAGE_BH
#undef FRAG_A
#undef FRAG_B
#undef LGKM0_FENCE
}

extern "C" void kernel_launch(void* const* d_in, const int* in_sizes, int n_in,
                              void* d_out, int out_size, void* d_ws, size_t ws_size,
                              hipStream_t stream) {
    const float* x    = (const float*)d_in[0];
    const float* Af   = (const float*)d_in[1];  // [2048][64]
    const float* Bf   = (const float*)d_in[2];  // [64][1152]
    const float* Sp   = (const float*)d_in[3];  // [768][3072]
    const float* bias = (const float*)d_in[4];  // [3072]
    float* out = (float*)d_out;

    unsigned short* xb = (unsigned short*)d_ws;                 // 25,165,824 B
    unsigned short* wt = xb + (size_t)M_TOT * K_TOT;            // + 4,718,592 B
    // W_tilde scratch in d_out's head; GEMM overwrites all of d_out after.
    float* wtmp = (float*)d_out;                                // 9,437,184 B

    hipLaunchKernelGGL(cvt_x_kernel, dim3(2048), dim3(256), 0, stream,
                       x, xb, M_TOT * K_TOT / 8);
    hipLaunchKernelGGL(wtilde_gemm_kernel, dim3(32 * 18), dim3(256), 0, stream,
                       Af, Bf, wtmp);
    hipLaunchKernelGGL(permute_w_kernel, dim3(12 * 48), dim3(256), 0, stream,
                       wtmp, Sp, wt);
    hipLaunchKernelGGL(gemm_bt_kernel, dim3(256), dim3(512),
                       0, stream, xb, wt, bias, out);
}

// Round 13
// 127.510 us; speedup vs baseline: 1.3238x; 1.3238x over previous
//
#include <hip/hip_runtime.h>
#include <hip/hip_bf16.h>
#include <stdint.h>

#define M_TOT 16384
#define N_TOT 3072
#define K_TOT 768

#define BM 256
#define BN 256
#define BK 32
#define NT (K_TOT / BK)   // 24 K-tiles

typedef __attribute__((ext_vector_type(8))) short short8;
typedef __attribute__((ext_vector_type(4))) float f32x4;

__device__ __forceinline__ unsigned short f2bf(float f) {
    union { float f; unsigned u; } v;
    v.f = f;
    unsigned r = v.u + 0x7FFFu + ((v.u >> 16) & 1u);  // round-to-nearest-even
    return (unsigned short)(r >> 16);
}

// ---------------- kernel 1: fused W-prep (512 blocks) + x-cvt (2048 blocks) --
// prep block b<512: (m1, n1_0=4*n1-quad).  Computes 4 W_tilde rows
// (a_row @ B, B streamed coalesced), adds Sparse, writes Wt[c][r] bf16
// transposed.  cvt block b>=512: fp32->bf16 of x, 8 elems/thread/iter.
// One dispatch: prep's L2-bound work overlaps cvt's HBM-bound stream.
__global__ __launch_bounds__(384) void prep_cvt_kernel(
    const float* __restrict__ Af, const float* __restrict__ Bf,
    const float* __restrict__ Sp, const float* __restrict__ x,
    unsigned short* __restrict__ xb, unsigned short* __restrict__ Wt) {
    __shared__ float a_sh[4][64];
    __shared__ float wrow[4][1160];   // 4 rows x 1152 (+8 pad)
    const int tid = threadIdx.x;
    const int b = blockIdx.x;

    if (b < 512) {
        const int m1 = b >> 4;             // 0..31
        const int n10 = (b & 15) * 4;      // 0..60
        if (tid < 256) {
            int rr = tid >> 6, k = tid & 63;
            a_sh[rr][k] = Af[(size_t)(m1 * 64 + n10 + rr) * 64 + k];
        }
        __syncthreads();
        float acc[4][3] = {};
        #pragma unroll 2
        for (int k = 0; k < 64; ++k) {
            const float* brow = Bf + (size_t)k * 1152;
            float b0 = brow[tid], b1 = brow[tid + 384], b2 = brow[tid + 768];
            #pragma unroll
            for (int rr = 0; rr < 4; ++rr) {
                float a = a_sh[rr][k];
                acc[rr][0] = fmaf(a, b0, acc[rr][0]);
                acc[rr][1] = fmaf(a, b1, acc[rr][1]);
                acc[rr][2] = fmaf(a, b2, acc[rr][2]);
            }
        }
        #pragma unroll
        for (int rr = 0; rr < 4; ++rr) {
            wrow[rr][tid] = acc[rr][0];
            wrow[rr][tid + 384] = acc[rr][1];
            wrow[rr][tid + 768] = acc[rr][2];
        }
        __syncthreads();
        // write phase: unit u<192: rr = u/48, n2 = u%48 -> 24 m2-contig bf16
        if (tid < 192) {
            const int rr = tid / 48, n2 = tid % 48;
            const int c = (n10 + rr) * 48 + n2;          // Wt col (N index)
            const int r0 = m1 * 24;                      // Wt row base (K index)
            unsigned w[12];
            #pragma unroll
            for (int t2 = 0; t2 < 12; ++t2) {
                float lo = wrow[rr][(2 * t2) * 48 + n2]
                         + Sp[(size_t)(r0 + 2 * t2) * 3072 + c];
                float hi = wrow[rr][(2 * t2 + 1) * 48 + n2]
                         + Sp[(size_t)(r0 + 2 * t2 + 1) * 3072 + c];
                w[t2] = (unsigned)f2bf(lo) | ((unsigned)f2bf(hi) << 16);
            }
            uint4* d4 = reinterpret_cast<uint4*>(Wt + (size_t)c * 768 + r0);
            d4[0] = (uint4){w[0], w[1], w[2], w[3]};
            d4[1] = (uint4){w[4], w[5], w[6], w[7]};
            d4[2] = (uint4){w[8], w[9], w[10], w[11]};
        }
    } else {
        const int n8 = M_TOT * K_TOT / 8;
        int i = (b - 512) * 384 + tid;
        const int stride = 2048 * 384;
        const float4* xv = reinterpret_cast<const float4*>(x);
        uint4* ov = reinterpret_cast<uint4*>(xb);
        for (; i < n8; i += stride) {
            float4 a = xv[2 * i], c = xv[2 * i + 1];
            uint4 o;
            o.x = (unsigned)f2bf(a.x) | ((unsigned)f2bf(a.y) << 16);
            o.y = (unsigned)f2bf(a.z) | ((unsigned)f2bf(a.w) << 16);
            o.z = (unsigned)f2bf(c.x) | ((unsigned)f2bf(c.y) << 16);
            o.w = (unsigned)f2bf(c.z) | ((unsigned)f2bf(c.w) << 16);
            ov[i] = o;
        }
    }
}

// ---------------- kernel 2: R11 GEMM (best measured: 112.7us), unchanged -----
// A  : [16384][768] bf16; Bt : [3072][768] bf16; C = A@Bt^T + bias.
// 8 waves (2Mx4N), BK=32, 4 LDS buffers, counted vmcnt, swapped-operand
// MFMA (mfma(b,a,acc)) -> lane owns M-row x 4 N-cols -> float4 C-stores.
__device__ __forceinline__ void gld16(const void* g, void* l) {
    __builtin_amdgcn_global_load_lds(
        (const __attribute__((address_space(1))) void*)g,
        (__attribute__((address_space(3))) void*)l, 16, 0, 0);
}

__global__ __launch_bounds__(512, 2) void gemm_bt_kernel(
    const unsigned short* __restrict__ A, const unsigned short* __restrict__ Bt,
    const float* __restrict__ bias, float* __restrict__ C) {
    __shared__ unsigned short As[4][BM * BK];
    __shared__ unsigned short Bs[4][BN * BK];

    const int tid = threadIdx.x;
    const int lane = tid & 63;
    const int wid = tid >> 6;      // 0..7
    const int wr = wid >> 2;       // 0..1  (M half)
    const int wc = wid & 3;        // 0..3  (N quarter)

    // XCD-aware swizzle: 768 blocks = 8 XCDs x 96
    const int wg = (blockIdx.x & 7) * 96 + (blockIdx.x >> 3);
    const int bm = wg / (N_TOT / BN), bn = wg % (N_TOT / BN);
    const int brow = bm * BM, bcol = bn * BN;

    const int srow = tid >> 2;                                   // 0..127
    const int soff = (((tid & 3) ^ ((tid >> 3) & 3)) << 4);      // bytes
    const char* pA = (const char*)A + ((size_t)(brow + srow) * K_TOT) * 2 + soff;
    const char* pB = (const char*)Bt + ((size_t)(bcol + srow) * K_TOT) * 2 + soff;
    const size_t row128 = (size_t)128 * K_TOT * 2;
    const int tid16 = tid * 16;

#define STAGE_AH(u) do { const char* s_ = pA + (size_t)(u) * (BK * 2);           \
        gld16(s_,          (char*)&As[(u) & 3][0] + tid16);                      \
        gld16(s_ + row128, (char*)&As[(u) & 3][0] + tid16 + 8192); } while (0)
#define STAGE_BH(u) do { const char* s_ = pB + (size_t)(u) * (BK * 2);           \
        gld16(s_,          (char*)&Bs[(u) & 3][0] + tid16);                      \
        gld16(s_ + row128, (char*)&Bs[(u) & 3][0] + tid16 + 8192); } while (0)

    const int la = lane & 15;
    const int g4 = lane >> 4;
    const int swb = ((g4 ^ ((lane >> 1) & 3)) << 4);   // byte in row
#define FRAG_A(bu, r) (*(const short8*)((const char*)&As[bu][0] + (r) * 64 + swb))
#define FRAG_B(bu, r) (*(const short8*)((const char*)&Bs[bu][0] + (r) * 64 + swb))

#define LGKM0_FENCE() do {                                                       \
        asm volatile("s_waitcnt lgkmcnt(0)" ::: "memory");                       \
        __builtin_amdgcn_sched_barrier(0); } while (0)

    f32x4 acc[8][4];
    #pragma unroll
    for (int m = 0; m < 8; ++m)
        #pragma unroll
        for (int n = 0; n < 4; ++n)
            acc[m][n] = (f32x4){0.f, 0.f, 0.f, 0.f};

    STAGE_AH(0); STAGE_BH(0);
    STAGE_AH(1); STAGE_BH(1);
    STAGE_AH(2); STAGE_BH(2);
    asm volatile("s_waitcnt vmcnt(8)" ::: "memory");
    __builtin_amdgcn_s_barrier();

    const int arow = wr * 128;
    const int bcolw = wc * 64;
    for (int t = 0; t < NT; ++t) {
        const int bu = t & 3;
        short8 a0[4], b0[4];
        // ================= phase A: quadrant m0-3 x n0-3 =====================
        #pragma unroll
        for (int n = 0; n < 4; ++n) b0[n] = FRAG_B(bu, bcolw + n * 16 + la);
        #pragma unroll
        for (int m = 0; m < 4; ++m) a0[m] = FRAG_A(bu, arow + m * 16 + la);
        if (t < NT - 3) STAGE_AH(t + 3);
        __builtin_amdgcn_s_barrier();
        LGKM0_FENCE();
        __builtin_amdgcn_s_setprio(1);
        #pragma unroll
        for (int m = 0; m < 4; ++m)
            #pragma unroll
            for (int n = 0; n < 4; ++n)
                acc[m][n] = __builtin_amdgcn_mfma_f32_16x16x32_bf16(
                    b0[n], a0[m], acc[m][n], 0, 0, 0);   // SWAPPED operands
        __builtin_amdgcn_s_setprio(0);
        __builtin_amdgcn_s_barrier();
        // ================= phase B: quadrant m4-7 x n0-3 =====================
        #pragma unroll
        for (int m = 0; m < 4; ++m) a0[m] = FRAG_A(bu, arow + 64 + m * 16 + la);
        if (t < NT - 3) STAGE_BH(t + 3);
        if (t < NT - 3)       asm volatile("s_waitcnt vmcnt(8)" ::: "memory");
        else if (t == NT - 3) asm volatile("s_waitcnt vmcnt(4)" ::: "memory");
        else if (t == NT - 2) asm volatile("s_waitcnt vmcnt(0)" ::: "memory");
        __builtin_amdgcn_s_barrier();
        LGKM0_FENCE();
        __builtin_amdgcn_s_setprio(1);
        #pragma unroll
        for (int m = 0; m < 4; ++m)
            #pragma unroll
            for (int n = 0; n < 4; ++n)
                acc[4 + m][n] = __builtin_amdgcn_mfma_f32_16x16x32_bf16(
                    b0[n], a0[m], acc[4 + m][n], 0, 0, 0);   // SWAPPED
        __builtin_amdgcn_s_setprio(0);
        __builtin_amdgcn_s_barrier();
    }

    // ---- epilogue: lane owns M-row (la) x 4 N-cols (g4*4+j) -> float4 stores
    #pragma unroll
    for (int n = 0; n < 4; ++n) {
        const int gc = bcol + bcolw + n * 16 + g4 * 4;
        const f32x4 bv = *reinterpret_cast<const f32x4*>(&bias[gc]);
        #pragma unroll
        for (int m = 0; m < 8; ++m) {
            const int gr = brow + arow + m * 16 + la;
            f32x4 o = {acc[m][n][0] + bv[0], acc[m][n][1] + bv[1],
                       acc[m][n][2] + bv[2], acc[m][n][3] + bv[3]};
            *reinterpret_cast<f32x4*>(&C[(size_t)gr * N_TOT + gc]) = o;
        }
    }
#undef STAGE_AH
#undef STAGE_BH
#undef FRAG_A
#undef FRAG_B
#undef LGKM0_FENCE
}

extern "C" void kernel_launch(void* const* d_in, const int* in_sizes, int n_in,
                              void* d_out, int out_size, void* d_ws, size_t ws_size,
                              hipStream_t stream) {
    const float* x    = (const float*)d_in[0];
    const float* Af   = (const float*)d_in[1];  // [2048][64]
    const float* Bf   = (const float*)d_in[2];  // [64][1152]
    const float* Sp   = (const float*)d_in[3];  // [768][3072]
    const float* bias = (const float*)d_in[4];  // [3072]
    float* out = (float*)d_out;

    unsigned short* xb = (unsigned short*)d_ws;                 // 25,165,824 B
    unsigned short* wt = xb + (size_t)M_TOT * K_TOT;            // + 4,718,592 B

    hipLaunchKernelGGL(prep_cvt_kernel, dim3(512 + 2048), dim3(384), 0, stream,
                       Af, Bf, Sp, x, xb, wt);
    hipLaunchKernelGGL(gemm_bt_kernel,
                       dim3((M_TOT / BM) * (N_TOT / BN)), dim3(512),
                       0, stream, xb, wt, bias, out);
}